// Round 1
// baseline (352.019 us; speedup 1.0000x reference)
//
#include <hip/hip_runtime.h>

#define BM 128
#define BN 128
#define BK 64

typedef __bf16 bf16x8 __attribute__((ext_vector_type(8)));
typedef float f32x4 __attribute__((ext_vector_type(4)));

typedef const __attribute__((address_space(1))) unsigned int* as1_u32_ptr;
typedef __attribute__((address_space(3))) unsigned int* as3_u32_ptr;

__device__ __forceinline__ void gload_lds16(const void* g, void* l) {
    __builtin_amdgcn_global_load_lds((as1_u32_ptr)g, (as3_u32_ptr)l, 16, 0, 0);
}

__device__ __forceinline__ unsigned short f2bf(float f) {
    unsigned u = __float_as_uint(f);
    u += 0x7fffu + ((u >> 16) & 1u);   // RNE
    return (unsigned short)(u >> 16);
}

// ---------------------------------------------------------------------------
// cast f32 -> bf16, 4 elements/thread
__global__ void cast_f32_bf16(const float* __restrict__ src,
                              unsigned short* __restrict__ dst, int n4) {
    int i = blockIdx.x * 256 + threadIdx.x;
    if (i < n4) {
        float4 v = ((const float4*)src)[i];
        ushort4 o;
        o.x = f2bf(v.x); o.y = f2bf(v.y); o.z = f2bf(v.z); o.w = f2bf(v.w);
        ((ushort4*)dst)[i] = o;
    }
}

// ---------------------------------------------------------------------------
// task_mats [8][K=1024][N=1024] f32  ->  tasksT [8][N][K] bf16  (transpose+cast)
__global__ void transpose_cast(const float* __restrict__ src,
                               unsigned short* __restrict__ dst) {
    __shared__ float tile[32][33];
    const int j = blockIdx.z;
    const float* M = src + (size_t)j * 1048576;
    unsigned short* Mt = dst + (size_t)j * 1048576;
    const int n0 = blockIdx.x * 32, k0 = blockIdx.y * 32;
    const int tx = threadIdx.x, ty = threadIdx.y;
#pragma unroll
    for (int r = 0; r < 32; r += 8)
        tile[ty + r][tx] = M[(size_t)(k0 + ty + r) * 1024 + n0 + tx];
    __syncthreads();
#pragma unroll
    for (int r = 0; r < 32; r += 8)
        Mt[(size_t)(n0 + ty + r) * 1024 + k0 + tx] = f2bf(tile[tx][ty + r]);
}

// ---------------------------------------------------------------------------
// coeff[b][t] = b2[t] + dot(h[b,:], W2[t,:])   (B=4096, T=8, H=256)
__global__ void coeff_kernel(const float* __restrict__ h, const float* __restrict__ W2,
                             const float* __restrict__ b2, float* __restrict__ coeff) {
    __shared__ float w2s[2048];
    const int tid = threadIdx.x;
    for (int i = tid; i < 2048; i += 256) w2s[i] = W2[i];
    __syncthreads();
    const int t = tid & 7;
    const int b = blockIdx.x * 32 + (tid >> 3);
    const float* hr = h + (size_t)b * 256;
    const float* wr = w2s + t * 256;
    float s = b2[t];
#pragma unroll 8
    for (int i = 0; i < 256; ++i) s += hr[i] * wr[i];
    coeff[b * 8 + t] = s;
}

// ---------------------------------------------------------------------------
// GEMM: out = A[M][K](bf16) x Bt[N][K](bf16)^T  with mode-specific epilogue.
// MODE 0 (H):     outf = relu(acc + bias[n])
// MODE 1 (STEP):  v = xf32 + coeff[row*8+j]*acc ; outf = v ; outb = bf16(v)
// MODE 2 (FINAL): outf = acc
// 128x128 tile, BK=64, 4 waves (2x2), 16x16x32 bf16 MFMA, global_load_lds w16,
// XOR-swizzled LDS (unit' = unit ^ (row&7)) for conflict-free ds_read_b128.
template <int MODE>
__launch_bounds__(256, 2)
__global__ void gemm_kernel(const unsigned short* __restrict__ A,
                            const unsigned short* __restrict__ Bt,
                            int M, int N, int K,
                            const float* __restrict__ xf32,
                            const float* __restrict__ coeff, int jidx,
                            const float* __restrict__ bias,
                            float* __restrict__ outf,
                            unsigned short* __restrict__ outb) {
    __shared__ __align__(16) unsigned short As[BM * BK];
    __shared__ __align__(16) unsigned short Bs[BN * BK];

    const int tid = threadIdx.x;
    const int wid = tid >> 6;
    const int lane = tid & 63;
    const int s = lane & 15, q = lane >> 4;
    const int wm = (wid >> 1) * 64, wn = (wid & 1) * 64;
    const int bm = blockIdx.y * BM, bn = blockIdx.x * BN;

    f32x4 acc[4][4] = {};

    // staging: chunk c (0..15) = 8 rows of 64 els; lane covers row c*8+(lane>>3),
    // 16B unit (lane&7); global k-unit is swizzled: u_log = (lane&7) ^ (lane>>3)
    const int rsub = lane >> 3;
    const int usw = ((lane & 7) ^ rsub) * 8;
    const unsigned short* Ag = A + (size_t)(bm + rsub) * K + usw;
    const unsigned short* Bg = Bt + (size_t)(bn + rsub) * K + usw;
    const int c0 = wid * 4;

    for (int k0 = 0; k0 < K; k0 += BK) {
        __syncthreads();   // previous tile fully consumed
#pragma unroll
        for (int i = 0; i < 4; ++i) {
            const int c = c0 + i;
            gload_lds16(Ag + (size_t)(c * 8) * K + k0, As + c * 512);
            gload_lds16(Bg + (size_t)(c * 8) * K + k0, Bs + c * 512);
        }
        __syncthreads();   // compiler drains vmcnt(0) before s_barrier

#pragma unroll
        for (int kk = 0; kk < BK; kk += 32) {
            bf16x8 av[4], bv[4];
            const int ub = kk >> 3;
#pragma unroll
            for (int t = 0; t < 4; ++t) {
                const int ua = ((ub + q) ^ (s & 7)) * 8;
                av[t] = *(const bf16x8*)(As + (wm + t * 16 + s) * 64 + ua);
                bv[t] = *(const bf16x8*)(Bs + (wn + t * 16 + s) * 64 + ua);
            }
#pragma unroll
            for (int mi = 0; mi < 4; ++mi)
#pragma unroll
                for (int ni = 0; ni < 4; ++ni)
                    acc[mi][ni] = __builtin_amdgcn_mfma_f32_16x16x32_bf16(
                        av[mi], bv[ni], acc[mi][ni], 0, 0, 0);
        }
    }

    // epilogue: C/D layout col = lane&15, row = (lane>>4)*4 + reg  [m89-verified]
    const int colb = bn + wn + s;
#pragma unroll
    for (int mi = 0; mi < 4; ++mi) {
        const int row0 = bm + wm + mi * 16 + q * 4;
        float cf[4];
        if (MODE == 1) {
#pragma unroll
            for (int r = 0; r < 4; ++r) cf[r] = coeff[(size_t)(row0 + r) * 8 + jidx];
        }
#pragma unroll
        for (int ni = 0; ni < 4; ++ni) {
            const int col = colb + ni * 16;
#pragma unroll
            for (int r = 0; r < 4; ++r) {
                const size_t off = (size_t)(row0 + r) * N + col;
                float v = acc[mi][ni][r];
                if (MODE == 0) {
                    v += bias[col];
                    v = v > 0.f ? v : 0.f;
                    outf[off] = v;
                } else if (MODE == 1) {
                    v = xf32[off] + cf[r] * v;
                    outf[off] = v;
                    outb[off] = f2bf(v);
                } else {
                    outf[off] = v;
                }
            }
        }
    }
}

// ---------------------------------------------------------------------------
extern "C" void kernel_launch(void* const* d_in, const int* in_sizes, int n_in,
                              void* d_out, int out_size, void* d_ws, size_t ws_size,
                              hipStream_t stream) {
    const float* features = (const float*)d_in[0];  // [4096][1024]
    const float* W1 = (const float*)d_in[1];        // [256][1024]
    const float* b1 = (const float*)d_in[2];        // [256]
    const float* W2 = (const float*)d_in[3];        // [8][256]
    const float* b2 = (const float*)d_in[4];        // [8]
    const float* task = (const float*)d_in[5];      // [8][1024][1024]
    const float* Wp = (const float*)d_in[6];        // [1024][1024]

    char* ws = (char*)d_ws;
    unsigned short* tasksT = (unsigned short*)(ws);             // 16 MB  [8][N][K] bf16
    unsigned short* Wpbf   = (unsigned short*)(ws + 16777216);  //  2 MB  [N][K] bf16
    unsigned short* W1bf   = (unsigned short*)(ws + 18874368);  // .5 MB  [H][D] bf16
    unsigned short* Xbf0   = (unsigned short*)(ws + 19398656);  //  8 MB
    unsigned short* Xbf1   = (unsigned short*)(ws + 27787264);  //  8 MB
    float* F0              = (float*)(ws + 36175872);           // 16 MB fp32 master ping
    float* coeffp          = (float*)(ws + 52953088);           // 128 KB
    float* h               = (float*)(ws + 36175872);           // alias F0 (dead before step0 writes)
    float* outf32 = (float*)d_out;                              // fp32 master pong + final out

    // one-time conversions (re-done every call; ws is re-poisoned by harness)
    cast_f32_bf16<<<4096, 256, 0, stream>>>(features, Xbf0, 1048576);
    cast_f32_bf16<<<256, 256, 0, stream>>>(W1, W1bf, 65536);
    cast_f32_bf16<<<1024, 256, 0, stream>>>(Wp, Wpbf, 262144);
    transpose_cast<<<dim3(32, 32, 8), dim3(32, 8, 1), 0, stream>>>(task, tasksT);

    // metanet: h = relu(X @ W1^T + b1)  [4096 x 256], then coeff [4096 x 8]
    gemm_kernel<0><<<dim3(2, 32), 256, 0, stream>>>(Xbf0, W1bf, 4096, 256, 1024,
                                                    nullptr, nullptr, 0, b1, h, nullptr);
    coeff_kernel<<<128, 256, 0, stream>>>(h, W2, b2, coeffp);

    // 8 sequential soft task-vector steps
    for (int j = 0; j < 8; ++j) {
        const unsigned short* Abf = (j & 1) ? Xbf1 : Xbf0;
        unsigned short* Obf = (j & 1) ? Xbf0 : Xbf1;
        const float* xin = (j == 0) ? features : ((j & 1) ? F0 : outf32);
        float* xout = (j & 1) ? outf32 : F0;
        gemm_kernel<1><<<dim3(8, 32), 256, 0, stream>>>(
            Abf, tasksT + (size_t)j * 1048576, 4096, 1024, 1024,
            xin, coeffp, j, nullptr, xout, Obf);
    }

    // final projection: out = X8 @ Wp^T   (A = Xbf0 after step 7)
    gemm_kernel<2><<<dim3(8, 32), 256, 0, stream>>>(Xbf0, Wpbf, 4096, 1024, 1024,
                                                    nullptr, nullptr, 0, nullptr,
                                                    outf32, nullptr);
}